// Round 6
// baseline (372.959 us; speedup 1.0000x reference)
//
#include <hip/hip_runtime.h>
#include <math.h>

#define D_MODEL 1024
#define SEQ 2048
#define SCALE 0.03125f
#define NBLK 512u

using bf16x8 = __attribute__((ext_vector_type(8))) short;
using f32x4  = __attribute__((ext_vector_type(4))) float;

__device__ __forceinline__ unsigned short f2bf(float f) {
  union { float f; unsigned int u; } v; v.f = f;
  return (unsigned short)((v.u + 0x7fffu + ((v.u >> 16) & 1u)) >> 16);
}

__device__ __forceinline__ void async_cp16(const void* g, void* l) {
  __builtin_amdgcn_global_load_lds(
      (const __attribute__((address_space(1))) void*)g,
      (__attribute__((address_space(3))) void*)l, 16, 0, 0);
}

// ----------------------------------------------------------------------------
// Hand-rolled grid barrier (no cooperative-launch dependency).
// One counter per barrier instance, zeroed by hipMemsetAsync before launch.
// Correct because all 512 blocks are co-resident by construction:
// LDS 67.6 KB -> hard cap 2 blocks/CU; grid = 2 x 256 CUs.
// ----------------------------------------------------------------------------
__device__ __forceinline__ void grid_barrier(unsigned int* cnt) {
  __syncthreads();
  if (threadIdx.x == 0) {
    __threadfence();  // release: flush this block's writes to device scope
    __hip_atomic_fetch_add(cnt, 1u, __ATOMIC_ACQ_REL, __HIP_MEMORY_SCOPE_AGENT);
    while (__hip_atomic_load(cnt, __ATOMIC_ACQUIRE, __HIP_MEMORY_SCOPE_AGENT) <
           NBLK) {
      __builtin_amdgcn_s_sleep(8);
    }
    __threadfence();  // acquire: invalidate stale cache before phase reads
  }
  __syncthreads();
}

// ============================================================================
// Round-4 proven GEMM core: 128x128 tile, 256 threads (4 waves, 2M x 2N),
// BK=64, double-buffered LDS = 64 KiB. LDS swizzle: 16B chunk c of row r at
// physical chunk c^(r&7) (2-way bank alias = free; 0 conflicts measured).
// Staging pre-swizzles the GLOBAL source (global_load_lds writes linearly).
// ============================================================================

__device__ __forceinline__ const unsigned short* sptr(
    const unsigned short* base, int row0, int t) {
  const int rr = t >> 3;
  const int ck = (t & 7) ^ (rr & 7);
  return base + (size_t)(row0 + rr) * D_MODEL + ck * 8;
}

#define STG8(KT, BUF) {                                                    \
    const unsigned short* a_ = sA + (KT) * 64;                             \
    const unsigned short* b_ = sB + (KT) * 64;                             \
    unsigned short* da_ = As + (BUF) * 8192 + t * 8;                       \
    unsigned short* db_ = Bs + (BUF) * 8192 + t * 8;                       \
    async_cp16(a_,                 da_);                                   \
    async_cp16(a_ + 32 * D_MODEL,  da_ + 2048);                            \
    async_cp16(a_ + 64 * D_MODEL,  da_ + 4096);                            \
    async_cp16(a_ + 96 * D_MODEL,  da_ + 6144);                            \
    async_cp16(b_,                 db_);                                   \
    async_cp16(b_ + 32 * D_MODEL,  db_ + 2048);                            \
    async_cp16(b_ + 64 * D_MODEL,  db_ + 4096);                            \
    async_cp16(b_ + 96 * D_MODEL,  db_ + 6144);                            \
  }

__device__ __forceinline__ void gemm128_bk64(
    const unsigned short* sA, const unsigned short* sB,
    unsigned short* As, unsigned short* Bs, int t, f32x4 acc[4][4]) {
  const int lane = t & 63, w = t >> 6;
  const int wm = w >> 1, wn = w & 1;
  const int l16 = lane & 15, quad = lane >> 4, x7 = l16 & 7;
  const int c0 = (quad ^ x7) * 8, c1 = ((4 | quad) ^ x7) * 8;

  STG8(0, 0);
  __syncthreads();

  #pragma unroll 2
  for (int kk = 0; kk < 16; ++kk) {
    const int cur = (kk & 1) * 8192;
    if (kk < 15) STG8(kk + 1, (kk & 1) ^ 1);
    bf16x8 afr[4][2], bfr[4][2];
    #pragma unroll
    for (int mt = 0; mt < 4; mt++) {
      const int base = cur + (wm * 64 + mt * 16 + l16) * 64;
      afr[mt][0] = *(const bf16x8*)(As + base + c0);
      afr[mt][1] = *(const bf16x8*)(As + base + c1);
    }
    #pragma unroll
    for (int nt = 0; nt < 4; nt++) {
      const int base = cur + (wn * 64 + nt * 16 + l16) * 64;
      bfr[nt][0] = *(const bf16x8*)(Bs + base + c0);
      bfr[nt][1] = *(const bf16x8*)(Bs + base + c1);
    }
    #pragma unroll
    for (int ks = 0; ks < 2; ks++)
      #pragma unroll
      for (int mt = 0; mt < 4; mt++)
        #pragma unroll
        for (int nt = 0; nt < 4; nt++)
          acc[mt][nt] = __builtin_amdgcn_mfma_f32_16x16x32_bf16(
              afr[mt][ks], bfr[nt][ks], acc[mt][nt], 0, 0, 0);
    __syncthreads();
  }
}

__device__ __forceinline__ void store_c_bf16(f32x4 acc[4][4],
                                             unsigned short* C, int ldc,
                                             int m0, int n0, int tid) {
  const int lane = tid & 63, w = tid >> 6;
  const int wm = w >> 1, wn = w & 1;
  const int l16 = lane & 15, quad = lane >> 4;
  #pragma unroll
  for (int mt = 0; mt < 4; mt++) {
    #pragma unroll
    for (int r = 0; r < 4; r++) {
      const int row = m0 + wm * 64 + mt * 16 + quad * 4 + r;
      unsigned short* cp = C + (size_t)row * ldc + n0 + wn * 64 + l16;
      #pragma unroll
      for (int nt = 0; nt < 4; nt++) cp[nt * 16] = f2bf(acc[mt][nt][r]);
    }
  }
}

// ============================================================================
// Mega kernel: all phases in ONE plain launch with hand-rolled grid barriers.
// grid = 512 x 256, __launch_bounds__(256,2), LDS 67.6 KiB -> exactly
// 2 blocks/CU x 256 CU co-resident.
// P0 wcvt -> bar0 -> P1 {prep_x(blk<448) || wmm(blk>=448)} -> bar1
//   -> P2 zgen (XCD-rectangled) -> bar2 -> P3 zxt (2 tiles/block, T1 map).
// ============================================================================
__global__ __launch_bounds__(256, 2) void mega_kernel(
    const float* __restrict__ x, const float* __restrict__ Wq,
    const float* __restrict__ bq, const float* __restrict__ Wk,
    const float* __restrict__ bk, const float* __restrict__ Wo,
    const float* __restrict__ bo, float* __restrict__ out,
    unsigned short* __restrict__ xb, unsigned short* __restrict__ Zb,
    unsigned short* __restrict__ Wqb, unsigned short* __restrict__ Wkb,
    unsigned short* __restrict__ Mt, float* __restrict__ tb,
    float* __restrict__ aa, float* __restrict__ bb, float* __restrict__ u,
    float* __restrict__ v, float* __restrict__ sc,
    unsigned int* __restrict__ bar) {
  __shared__ unsigned short As[2 * 8192], Bs[2 * 8192];
  __shared__ float bias4[4][128];  // tsi, tsa, tsj, tsb
  __shared__ float red3[3][4];
  const int blk = blockIdx.x, t = threadIdx.x;

  // ---------------- P0: wcvt (2049 items) ----------------
  for (int item = blk; item < 2049; item += 512) {
    float p;
    if (item < 2048) {
      const bool isq = item < 1024;
      const int row = item & 1023;
      const float* W = isq ? Wq : Wk;
      const float* bias = isq ? bk : bq;
      const float4 wv = ((const float4*)(W + (size_t)row * D_MODEL))[t];
      const float4 bv = ((const float4*)bias)[t];
      ushort4 o;
      o.x = f2bf(wv.x); o.y = f2bf(wv.y); o.z = f2bf(wv.z); o.w = f2bf(wv.w);
      ((ushort4*)((isq ? Wqb : Wkb) + (size_t)row * D_MODEL))[t] = o;
      p = wv.x * bv.x + wv.y * bv.y + wv.z * bv.z + wv.w * bv.w;
      #pragma unroll
      for (int off = 32; off > 0; off >>= 1) p += __shfl_down(p, off, 64);
      if ((t & 63) == 0) red3[0][t >> 6] = p;
      __syncthreads();
      if (t == 0)
        (isq ? u : v)[row] = red3[0][0] + red3[0][1] + red3[0][2] + red3[0][3];
      __syncthreads();
    } else {
      const float4 a = ((const float4*)bq)[t];
      const float4 b = ((const float4*)bk)[t];
      p = a.x * b.x + a.y * b.y + a.z * b.z + a.w * b.w;
      #pragma unroll
      for (int off = 32; off > 0; off >>= 1) p += __shfl_down(p, off, 64);
      if ((t & 63) == 0) red3[0][t >> 6] = p;
      __syncthreads();
      if (t == 0)
        sc[0] = SCALE * (red3[0][0] + red3[0][1] + red3[0][2] + red3[0][3]);
      __syncthreads();
    }
  }
  grid_barrier(bar + 0);

  // ------- P1: prep_x (blocks 0..447) || wmm (blocks 448..511) -------
  if (blk < 448) {
    const float4 wv = ((const float4*)Wo)[t];
    const float4 uv = ((const float4*)u)[t];
    const float4 vv = ((const float4*)v)[t];
    const float scv = sc[0];
    const float bov = bo[0];
    for (int m = blk; m < 8192; m += 448) {
      const float4 xv = ((const float4*)(x + (size_t)m * D_MODEL))[t];
      ushort4 o;
      o.x = f2bf(xv.x); o.y = f2bf(xv.y); o.z = f2bf(xv.z); o.w = f2bf(xv.w);
      ((ushort4*)(xb + (size_t)m * D_MODEL))[t] = o;
      float p0 = xv.x * wv.x + xv.y * wv.y + xv.z * wv.z + xv.w * wv.w;
      float p1 = xv.x * uv.x + xv.y * uv.y + xv.z * uv.z + xv.w * uv.w;
      float p2 = xv.x * vv.x + xv.y * vv.y + xv.z * vv.z + xv.w * vv.w;
      #pragma unroll
      for (int off = 32; off > 0; off >>= 1) {
        p0 += __shfl_down(p0, off, 64);
        p1 += __shfl_down(p1, off, 64);
        p2 += __shfl_down(p2, off, 64);
      }
      if ((t & 63) == 0) {
        red3[0][t >> 6] = p0; red3[1][t >> 6] = p1; red3[2][t >> 6] = p2;
      }
      __syncthreads();
      if (t == 0) {
        tb[m] = tanhf(red3[0][0] + red3[0][1] + red3[0][2] + red3[0][3] + bov);
        aa[m] = SCALE * (red3[1][0] + red3[1][1] + red3[1][2] + red3[1][3]) + scv;
        bb[m] = SCALE * (red3[2][0] + red3[2][1] + red3[2][2] + red3[2][3]);
      }
      __syncthreads();
    }
  } else {
    const int tile = blk - 448;  // 0..63
    const int m0 = (tile & 7) * 128, n0 = (tile >> 3) * 128;
    f32x4 acc[4][4];
    #pragma unroll
    for (int i = 0; i < 4; i++)
      #pragma unroll
      for (int j = 0; j < 4; j++) acc[i][j] = f32x4{0.f, 0.f, 0.f, 0.f};
    gemm128_bk64(sptr(Wkb, m0, t), sptr(Wqb, n0, t), As, Bs, t, acc);
    store_c_bf16(acc, Mt, D_MODEL, m0, n0, t);
  }
  grid_barrier(bar + 32);

  // ---------------- P2: zgen (512 tiles, XCD-rectangled) ----------------
  {
    const int xcd = blk & 7, q = blk >> 3;
    const int m0 = (xcd * 8 + (q & 7)) * 128;  // 8 m-panels per XCD
    const int n0 = (q >> 3) * 128;             // all 8 n-tiles (Mt fits L2)
    f32x4 acc[4][4];
    #pragma unroll
    for (int i = 0; i < 4; i++)
      #pragma unroll
      for (int j = 0; j < 4; j++) acc[i][j] = f32x4{0.f, 0.f, 0.f, 0.f};
    gemm128_bk64(sptr(xb, m0, t), sptr(Mt, n0, t), As, Bs, t, acc);
    store_c_bf16(acc, Zb, D_MODEL, m0, n0, t);
  }
  grid_barrier(bar + 64);

  // ---------------- P3: zxt (1024 tiles, 2 per block, T1 map) ----------------
  const int lane = t & 63, w = t >> 6;
  const int wm = w >> 1, wn = w & 1;
  const int l16 = lane & 15, quad = lane >> 4;
  for (int it = 0; it < 2; ++it) {
    const int n = blk + 512 * it;  // (n&7) invariant -> same XCD rectangle
    const int xcd = n & 7, q = n >> 3;
    const int b = q >> 5, r = q & 31;
    const int i0 = ((xcd >> 1) * 4 + (r >> 3)) * 128;
    const int j0 = ((xcd & 1) * 8 + (r & 7)) * 128;
    __syncthreads();  // protect bias4 from previous item's readers
    if (t < 128) {
      bias4[0][t] = tb[b * SEQ + i0 + t];
      bias4[1][t] = aa[b * SEQ + i0 + t];
    } else {
      bias4[2][t - 128] = tb[b * SEQ + j0 + t - 128];
      bias4[3][t - 128] = bb[b * SEQ + j0 + t - 128];
    }
    f32x4 acc[4][4];
    #pragma unroll
    for (int i = 0; i < 4; i++)
      #pragma unroll
      for (int j = 0; j < 4; j++) acc[i][j] = f32x4{0.f, 0.f, 0.f, 0.f};
    gemm128_bk64(sptr(Zb + (size_t)b * SEQ * D_MODEL, i0, t),
                 sptr(xb + (size_t)b * SEQ * D_MODEL, j0, t), As, Bs, t, acc);

    float tj[4], bj[4];
    #pragma unroll
    for (int nt = 0; nt < 4; nt++) {
      tj[nt] = bias4[2][wn * 64 + nt * 16 + l16];
      bj[nt] = bias4[3][wn * 64 + nt * 16 + l16];
    }
    #pragma unroll
    for (int mt = 0; mt < 4; mt++) {
      #pragma unroll
      for (int rr = 0; rr < 4; rr++) {
        const int il = wm * 64 + mt * 16 + quad * 4 + rr;
        const float ti = bias4[0][il];
        const float ai = bias4[1][il];
        float* cp =
            out + ((size_t)(b * SEQ + i0 + il)) * SEQ + j0 + wn * 64 + l16;
        #pragma unroll
        for (int nt = 0; nt < 4; nt++) {
          const float num = tj[nt] - ti;
          const float den = fmaf(-tj[nt], ti, 1.0f);
          const float obias = 5.0f * num * __builtin_amdgcn_rcpf(den);
          cp[nt * 16] = SCALE * acc[mt][nt][rr] + ai + bj[nt] + obias;
        }
      }
    }
  }
}

extern "C" void kernel_launch(void* const* d_in, const int* in_sizes, int n_in,
                              void* d_out, int out_size, void* d_ws,
                              size_t ws_size, hipStream_t stream) {
  const float* x  = (const float*)d_in[0];
  const float* Wq = (const float*)d_in[1];
  const float* bq = (const float*)d_in[2];
  const float* Wk = (const float*)d_in[3];
  const float* bk = (const float*)d_in[4];
  const float* Wo = (const float*)d_in[5];
  const float* bo = (const float*)d_in[6];
  float* out = (float*)d_out;

  char* ws = (char*)d_ws;
  unsigned short* xb  = (unsigned short*)(ws);                      // 16 MiB
  unsigned short* Zb  = (unsigned short*)(ws + (16ull << 20));      // 16 MiB
  unsigned short* Wqb = (unsigned short*)(ws + (32ull << 20));      // 2 MiB
  unsigned short* Wkb = (unsigned short*)(ws + (34ull << 20));      // 2 MiB
  unsigned short* Mt  = (unsigned short*)(ws + (36ull << 20));      // 2 MiB
  float* tb = (float*)(ws + (38ull << 20));                         // 32 KiB
  float* aa = (float*)(ws + (38ull << 20) + (32ull << 10));         // 32 KiB
  float* bb = (float*)(ws + (38ull << 20) + (64ull << 10));         // 32 KiB
  float* u  = (float*)(ws + (38ull << 20) + (96ull << 10));         // 4 KiB
  float* v  = (float*)(ws + (38ull << 20) + (100ull << 10));        // 4 KiB
  float* sc = (float*)(ws + (38ull << 20) + (104ull << 10));        // 4 B
  unsigned int* bar = (unsigned int*)(ws + (38ull << 20) + (112ull << 10));

  hipMemsetAsync(bar, 0, 512, stream);  // zero barrier counters each replay
  mega_kernel<<<NBLK, 256, 0, stream>>>(x, Wq, bq, Wk, bk, Wo, bo, out, xb, Zb,
                                        Wqb, Wkb, Mt, tb, aa, bb, u, v, sc,
                                        bar);
}

// Round 7
// 187.399 us; speedup vs baseline: 1.9902x; 1.9902x over previous
//
#include <hip/hip_runtime.h>
#include <math.h>

#define D_MODEL 1024
#define SEQ 2048
#define SCALE 0.03125f

using bf16x8 = __attribute__((ext_vector_type(8))) short;
using f32x4  = __attribute__((ext_vector_type(4))) float;

__device__ __forceinline__ unsigned short f2bf(float f) {
  union { float f; unsigned int u; } v; v.f = f;
  return (unsigned short)((v.u + 0x7fffu + ((v.u >> 16) & 1u)) >> 16);
}

__device__ __forceinline__ void async_cp16(const void* g, void* l) {
  __builtin_amdgcn_global_load_lds(
      (const __attribute__((address_space(1))) void*)g,
      (__attribute__((address_space(3))) void*)l, 16, 0, 0);
}

// ============================================================================
// Round-4 proven GEMM core (wmm/zgen): 128x128 tile, 256 threads, BK=64,
// double-buffered 64 KiB LDS -> 2 blocks/CU. Swizzle: 16B chunk c of row r
// at phys chunk c^(r&7); staging pre-swizzles the GLOBAL source.
// ============================================================================

__device__ __forceinline__ const unsigned short* sptr(
    const unsigned short* base, int row0, int t) {
  const int rr = t >> 3;
  const int ck = (t & 7) ^ (rr & 7);
  return base + (size_t)(row0 + rr) * D_MODEL + ck * 8;
}

#define STG8(KT, BUF) {                                                    \
    const unsigned short* a_ = sA + (KT) * 64;                             \
    const unsigned short* b_ = sB + (KT) * 64;                             \
    unsigned short* da_ = As + (BUF) * 8192 + t * 8;                       \
    unsigned short* db_ = Bs + (BUF) * 8192 + t * 8;                       \
    async_cp16(a_,                 da_);                                   \
    async_cp16(a_ + 32 * D_MODEL,  da_ + 2048);                            \
    async_cp16(a_ + 64 * D_MODEL,  da_ + 4096);                            \
    async_cp16(a_ + 96 * D_MODEL,  da_ + 6144);                            \
    async_cp16(b_,                 db_);                                   \
    async_cp16(b_ + 32 * D_MODEL,  db_ + 2048);                            \
    async_cp16(b_ + 64 * D_MODEL,  db_ + 4096);                            \
    async_cp16(b_ + 96 * D_MODEL,  db_ + 6144);                            \
  }

__device__ __forceinline__ void gemm128_bk64(
    const unsigned short* sA, const unsigned short* sB,
    unsigned short* As, unsigned short* Bs, int t, f32x4 acc[4][4]) {
  const int lane = t & 63, w = t >> 6;
  const int wm = w >> 1, wn = w & 1;
  const int l16 = lane & 15, quad = lane >> 4, x7 = l16 & 7;
  const int c0 = (quad ^ x7) * 8, c1 = ((4 | quad) ^ x7) * 8;

  STG8(0, 0);
  __syncthreads();

  #pragma unroll 2
  for (int kk = 0; kk < 16; ++kk) {
    const int cur = (kk & 1) * 8192;
    if (kk < 15) STG8(kk + 1, (kk & 1) ^ 1);
    bf16x8 afr[4][2], bfr[4][2];
    #pragma unroll
    for (int mt = 0; mt < 4; mt++) {
      const int base = cur + (wm * 64 + mt * 16 + l16) * 64;
      afr[mt][0] = *(const bf16x8*)(As + base + c0);
      afr[mt][1] = *(const bf16x8*)(As + base + c1);
    }
    #pragma unroll
    for (int nt = 0; nt < 4; nt++) {
      const int base = cur + (wn * 64 + nt * 16 + l16) * 64;
      bfr[nt][0] = *(const bf16x8*)(Bs + base + c0);
      bfr[nt][1] = *(const bf16x8*)(Bs + base + c1);
    }
    #pragma unroll
    for (int ks = 0; ks < 2; ks++)
      #pragma unroll
      for (int mt = 0; mt < 4; mt++)
        #pragma unroll
        for (int nt = 0; nt < 4; nt++)
          acc[mt][nt] = __builtin_amdgcn_mfma_f32_16x16x32_bf16(
              afr[mt][ks], bfr[nt][ks], acc[mt][nt], 0, 0, 0);
    __syncthreads();
  }
}

__device__ __forceinline__ void store_c_bf16(f32x4 acc[4][4],
                                             unsigned short* C, int ldc,
                                             int m0, int n0, int tid) {
  const int lane = tid & 63, w = tid >> 6;
  const int wm = w >> 1, wn = w & 1;
  const int l16 = lane & 15, quad = lane >> 4;
  #pragma unroll
  for (int mt = 0; mt < 4; mt++) {
    #pragma unroll
    for (int r = 0; r < 4; r++) {
      const int row = m0 + wm * 64 + mt * 16 + quad * 4 + r;
      unsigned short* cp = C + (size_t)row * ldc + n0 + wn * 64 + l16;
      #pragma unroll
      for (int nt = 0; nt < 4; nt++) cp[nt * 16] = f2bf(acc[mt][nt][r]);
    }
  }
}

// ---- wcvt: W fp32 -> bf16 rows; u = Wq bk, v = Wk bq, sc = scale*(bq.bk) ----
__global__ __launch_bounds__(256) void wcvt_kernel(
    const float* __restrict__ Wq, const float* __restrict__ Wk,
    const float* __restrict__ bq, const float* __restrict__ bk,
    unsigned short* __restrict__ Wqb, unsigned short* __restrict__ Wkb,
    float* __restrict__ u, float* __restrict__ v, float* __restrict__ sc) {
  const int blk = blockIdx.x, tid = threadIdx.x;
  __shared__ float red[4];
  float p;
  if (blk < 2048) {
    const bool isq = blk < 1024;
    const int row = blk & 1023;
    const float* W = isq ? Wq : Wk;
    const float* bias = isq ? bk : bq;
    const float4 wv = ((const float4*)(W + (size_t)row * D_MODEL))[tid];
    const float4 bv = ((const float4*)bias)[tid];
    ushort4 o;
    o.x = f2bf(wv.x); o.y = f2bf(wv.y); o.z = f2bf(wv.z); o.w = f2bf(wv.w);
    ((ushort4*)((isq ? Wqb : Wkb) + (size_t)row * D_MODEL))[tid] = o;
    p = wv.x * bv.x + wv.y * bv.y + wv.z * bv.z + wv.w * bv.w;
    #pragma unroll
    for (int off = 32; off > 0; off >>= 1) p += __shfl_down(p, off, 64);
    if ((tid & 63) == 0) red[tid >> 6] = p;
    __syncthreads();
    if (tid == 0) (isq ? u : v)[row] = red[0] + red[1] + red[2] + red[3];
  } else {
    const float4 a = ((const float4*)bq)[tid];
    const float4 b = ((const float4*)bk)[tid];
    p = a.x * b.x + a.y * b.y + a.z * b.z + a.w * b.w;
    #pragma unroll
    for (int off = 32; off > 0; off >>= 1) p += __shfl_down(p, off, 64);
    if ((tid & 63) == 0) red[tid >> 6] = p;
    __syncthreads();
    if (tid == 0) sc[0] = SCALE * (red[0] + red[1] + red[2] + red[3]);
  }
}

// ---- prep_x: xb=bf16(x); t=tanh(x.Wo+bo); aa=scale*(x.u)+sc; bb=scale*(x.v) ----
__global__ __launch_bounds__(256) void prep_x_kernel(
    const float* __restrict__ x, const float* __restrict__ Wo,
    const float* __restrict__ bo, const float* __restrict__ u,
    const float* __restrict__ v, const float* __restrict__ sc,
    unsigned short* __restrict__ xb, float* __restrict__ tb,
    float* __restrict__ aa, float* __restrict__ bb) {
  const int m = blockIdx.x, tid = threadIdx.x;
  const float4 xv = ((const float4*)(x + (size_t)m * D_MODEL))[tid];
  const float4 wv = ((const float4*)Wo)[tid];
  const float4 uv = ((const float4*)u)[tid];
  const float4 vv = ((const float4*)v)[tid];
  ushort4 o;
  o.x = f2bf(xv.x); o.y = f2bf(xv.y); o.z = f2bf(xv.z); o.w = f2bf(xv.w);
  ((ushort4*)(xb + (size_t)m * D_MODEL))[tid] = o;
  float p0 = xv.x * wv.x + xv.y * wv.y + xv.z * wv.z + xv.w * wv.w;
  float p1 = xv.x * uv.x + xv.y * uv.y + xv.z * uv.z + xv.w * uv.w;
  float p2 = xv.x * vv.x + xv.y * vv.y + xv.z * vv.z + xv.w * vv.w;
  #pragma unroll
  for (int off = 32; off > 0; off >>= 1) {
    p0 += __shfl_down(p0, off, 64);
    p1 += __shfl_down(p1, off, 64);
    p2 += __shfl_down(p2, off, 64);
  }
  __shared__ float red[3][4];
  if ((tid & 63) == 0) {
    red[0][tid >> 6] = p0; red[1][tid >> 6] = p1; red[2][tid >> 6] = p2;
  }
  __syncthreads();
  if (tid == 0) {
    tb[m] = tanhf(red[0][0] + red[0][1] + red[0][2] + red[0][3] + bo[0]);
    aa[m] = SCALE * (red[1][0] + red[1][1] + red[1][2] + red[1][3]) + sc[0];
    bb[m] = SCALE * (red[2][0] + red[2][1] + red[2][2] + red[2][3]);
  }
}

// ---- wmm: Mt[d2,d1] = sum_e Wk[d2,e]*Wq[d1,e]  (A=Wkb, B^T=Wqb) ----
__global__ __launch_bounds__(256, 2) void wmm_kernel(
    const unsigned short* __restrict__ Wkb,
    const unsigned short* __restrict__ Wqb, unsigned short* __restrict__ Mt) {
  const int m0 = blockIdx.x * 128, n0 = blockIdx.y * 128;
  __shared__ unsigned short As[2 * 8192], Bs[2 * 8192];
  const int t = threadIdx.x;
  f32x4 acc[4][4];
  #pragma unroll
  for (int i = 0; i < 4; i++)
    #pragma unroll
    for (int j = 0; j < 4; j++) acc[i][j] = f32x4{0.f, 0.f, 0.f, 0.f};
  gemm128_bk64(sptr(Wkb, m0, t), sptr(Wqb, n0, t), As, Bs, t, acc);
  store_c_bf16(acc, Mt, D_MODEL, m0, n0, t);
}

// ---- zgen: Zb = xb @ M  (B^T = Mt rows), XCD-rectangle map ----
// 512 blocks: xcd = id&7 owns m-panels xcd*8..xcd*8+7 x all 8 n-tiles
// -> per-XCD L2 set = 8 A-panels (2 MiB) + full Mt (2 MiB) = 4 MiB.
__global__ __launch_bounds__(256, 2) void zgen_kernel(
    const unsigned short* __restrict__ xb,
    const unsigned short* __restrict__ Mt, unsigned short* __restrict__ Zb) {
  const int id = blockIdx.y * 64 + blockIdx.x;
  const int xcd = id & 7, q = id >> 3;
  const int m0 = (xcd * 8 + (q & 7)) * 128;
  const int n0 = (q >> 3) * 128;
  __shared__ unsigned short As[2 * 8192], Bs[2 * 8192];
  const int t = threadIdx.x;
  f32x4 acc[4][4];
  #pragma unroll
  for (int i = 0; i < 4; i++)
    #pragma unroll
    for (int j = 0; j < 4; j++) acc[i][j] = f32x4{0.f, 0.f, 0.f, 0.f};
  gemm128_bk64(sptr(xb, m0, t), sptr(Mt, n0, t), As, Bs, t, acc);
  store_c_bf16(acc, Zb, D_MODEL, m0, n0, t);
}

// ============================================================================
// zxt: ring-3 counted-vmcnt core (T4) at 3 blocks/CU.
// 128x128 tile, 256 threads, BK=32; LDS = 3 x (A 8 KiB + B 8 KiB) = 48 KiB.
// Per K-tile: vmcnt(4) [retire current tile's 4 loads, leave next tile's 4
// in flight] -> s_barrier -> issue stage(kk+2) -> ds_read -> 16 MFMA.
// ONE barrier per K-tile, never vmcnt(0) in the main loop.
// Safety: buf[(kk+2)%3] was last ds_read in iter kk-1; those reads retired
// at their MFMAs' lgkmcnt, ordered before this barrier. Per-wave vmcnt is
// exact: 4 global_load_lds per tile; bias reads moved AFTER the loop.
// Swizzle: row r (4 chunks of 16B), phys chunk = c^(r&3); read chunk
// quad^(l16&3) -> 2-way bank alias (free). Staging pre-swizzles global src.
// ============================================================================
__global__ __launch_bounds__(256, 3) void zxt_kernel(
    const unsigned short* __restrict__ Zb, const unsigned short* __restrict__ xb,
    const float* __restrict__ tb, const float* __restrict__ aa,
    const float* __restrict__ bb, float* __restrict__ out) {
  __shared__ unsigned short As[3 * 4096], Bs[3 * 4096];
  // T1 XCD rectangle map (round-4 proven): n = z*256+y*16+x
  const int n = blockIdx.z * 256 + blockIdx.y * 16 + blockIdx.x;
  const int xcd = n & 7, q = n >> 3;
  const int b = q >> 5, r = q & 31;
  const int i0 = ((xcd >> 1) * 4 + (r >> 3)) * 128;
  const int j0 = ((xcd & 1) * 8 + (r & 7)) * 128;
  const int t = threadIdx.x;
  const int lane = t & 63, w = t >> 6;
  const int wm = w >> 1, wn = w & 1;
  const int l16 = lane & 15, quad = lane >> 4;
  const int ck8 = (quad ^ (l16 & 3)) * 8;  // phys chunk offset (shorts)

  // staging sources: thread t covers rows srow, srow+64; logical chunk
  // (t&3)^(srow&3) pre-swizzled into phys chunk t&3 (linear LDS dest t*8).
  const int srow = t >> 2;
  const int sc_ = (t & 3) ^ (srow & 3);
  const unsigned short* sA =
      Zb + ((size_t)b * SEQ + i0 + srow) * D_MODEL + sc_ * 8;
  const unsigned short* sB =
      xb + ((size_t)b * SEQ + j0 + srow) * D_MODEL + sc_ * 8;

  #define STG4(KT, BUFO) {                                        \
      async_cp16(sA + (KT) * 32,         As + (BUFO) + t * 8);    \
      async_cp16(sA + 65536 + (KT) * 32, As + (BUFO) + 2048 + t * 8); \
      async_cp16(sB + (KT) * 32,         Bs + (BUFO) + t * 8);    \
      async_cp16(sB + 65536 + (KT) * 32, Bs + (BUFO) + 2048 + t * 8); }

  f32x4 acc[4][4];
  #pragma unroll
  for (int i = 0; i < 4; i++)
    #pragma unroll
    for (int j = 0; j < 4; j++) acc[i][j] = f32x4{0.f, 0.f, 0.f, 0.f};

  STG4(0, 0);
  STG4(1, 4096);

  int cur = 0, stg = 8192;
  #pragma unroll 3
  for (int kk = 0; kk < 31; ++kk) {
    asm volatile("s_waitcnt vmcnt(4)" ::: "memory");
    __builtin_amdgcn_s_barrier();
    if (kk < 30) STG4(kk + 2, stg);
    bf16x8 afr[4], bfr[4];
    #pragma unroll
    for (int mt = 0; mt < 4; mt++)
      afr[mt] = *(const bf16x8*)(As + cur + (wm * 64 + mt * 16 + l16) * 32 + ck8);
    #pragma unroll
    for (int nt = 0; nt < 4; nt++)
      bfr[nt] = *(const bf16x8*)(Bs + cur + (wn * 64 + nt * 16 + l16) * 32 + ck8);
    #pragma unroll
    for (int mt = 0; mt < 4; mt++)
      #pragma unroll
      for (int nt = 0; nt < 4; nt++)
        acc[mt][nt] = __builtin_amdgcn_mfma_f32_16x16x32_bf16(
            afr[mt], bfr[nt], acc[mt][nt], 0, 0, 0);
    cur = (cur == 8192) ? 0 : cur + 4096;
    stg = (stg == 8192) ? 0 : stg + 4096;
  }
  // final K-tile (31): drain
  asm volatile("s_waitcnt vmcnt(0)" ::: "memory");
  __builtin_amdgcn_s_barrier();
  {
    bf16x8 afr[4], bfr[4];
    #pragma unroll
    for (int mt = 0; mt < 4; mt++)
      afr[mt] = *(const bf16x8*)(As + cur + (wm * 64 + mt * 16 + l16) * 32 + ck8);
    #pragma unroll
    for (int nt = 0; nt < 4; nt++)
      bfr[nt] = *(const bf16x8*)(Bs + cur + (wn * 64 + nt * 16 + l16) * 32 + ck8);
    #pragma unroll
    for (int mt = 0; mt < 4; mt++)
      #pragma unroll
      for (int nt = 0; nt < 4; nt++)
        acc[mt][nt] = __builtin_amdgcn_mfma_f32_16x16x32_bf16(
            afr[mt], bfr[nt], acc[mt][nt], 0, 0, 0);
  }

  // epilogue: bias terms read directly from global (L2-resident, broadcast)
  float tj[4], bj[4];
  #pragma unroll
  for (int nt = 0; nt < 4; nt++) {
    tj[nt] = tb[b * SEQ + j0 + wn * 64 + nt * 16 + l16];
    bj[nt] = bb[b * SEQ + j0 + wn * 64 + nt * 16 + l16];
  }
  #pragma unroll
  for (int mt = 0; mt < 4; mt++) {
    #pragma unroll
    for (int rr = 0; rr < 4; rr++) {
      const int il = wm * 64 + mt * 16 + quad * 4 + rr;
      const float ti = tb[b * SEQ + i0 + il];
      const float ai = aa[b * SEQ + i0 + il];
      float* cp =
          out + ((size_t)(b * SEQ + i0 + il)) * SEQ + j0 + wn * 64 + l16;
      #pragma unroll
      for (int nt = 0; nt < 4; nt++) {
        const float num = tj[nt] - ti;
        const float den = fmaf(-tj[nt], ti, 1.0f);
        const float obias = 5.0f * num * __builtin_amdgcn_rcpf(den);
        cp[nt * 16] = SCALE * acc[mt][nt][rr] + ai + bj[nt] + obias;
      }
    }
  }
}

extern "C" void kernel_launch(void* const* d_in, const int* in_sizes, int n_in,
                              void* d_out, int out_size, void* d_ws,
                              size_t ws_size, hipStream_t stream) {
  const float* x  = (const float*)d_in[0];
  const float* Wq = (const float*)d_in[1];
  const float* bq = (const float*)d_in[2];
  const float* Wk = (const float*)d_in[3];
  const float* bk = (const float*)d_in[4];
  const float* Wo = (const float*)d_in[5];
  const float* bo = (const float*)d_in[6];
  float* out = (float*)d_out;

  char* ws = (char*)d_ws;
  unsigned short* xb  = (unsigned short*)(ws);                      // 16 MiB
  unsigned short* Zb  = (unsigned short*)(ws + (16ull << 20));      // 16 MiB
  unsigned short* Wqb = (unsigned short*)(ws + (32ull << 20));      // 2 MiB
  unsigned short* Wkb = (unsigned short*)(ws + (34ull << 20));      // 2 MiB
  unsigned short* Mt  = (unsigned short*)(ws + (36ull << 20));      // 2 MiB
  float* tb = (float*)(ws + (38ull << 20));                         // 32 KiB
  float* aa = (float*)(ws + (38ull << 20) + (32ull << 10));         // 32 KiB
  float* bb = (float*)(ws + (38ull << 20) + (64ull << 10));         // 32 KiB
  float* u  = (float*)(ws + (38ull << 20) + (96ull << 10));         // 4 KiB
  float* v  = (float*)(ws + (38ull << 20) + (100ull << 10));        // 4 KiB
  float* sc = (float*)(ws + (38ull << 20) + (104ull << 10));        // 4 B

  wcvt_kernel<<<2049, 256, 0, stream>>>(Wq, Wk, bq, bk, Wqb, Wkb, u, v, sc);
  prep_x_kernel<<<8192, 256, 0, stream>>>(x, Wo, bo, u, v, sc, xb, tb, aa, bb);
  wmm_kernel<<<dim3(8, 8), 256, 0, stream>>>(Wkb, Wqb, Mt);
  zgen_kernel<<<dim3(64, 8), 256, 0, stream>>>(xb, Mt, Zb);
  zxt_kernel<<<dim3(16, 16, 4), 256, 0, stream>>>(Zb, xb, tb, aa, bb, out);
}

// Round 8
// 184.159 us; speedup vs baseline: 2.0252x; 1.0176x over previous
//
#include <hip/hip_runtime.h>
#include <math.h>

#define D_MODEL 1024
#define SEQ 2048
#define SCALE 0.03125f

using bf16x8 = __attribute__((ext_vector_type(8))) short;
using f32x4  = __attribute__((ext_vector_type(4))) float;

__device__ __forceinline__ unsigned short f2bf(float f) {
  union { float f; unsigned int u; } v; v.f = f;
  return (unsigned short)((v.u + 0x7fffu + ((v.u >> 16) & 1u)) >> 16);
}

__device__ __forceinline__ void async_cp16(const void* g, void* l) {
  __builtin_amdgcn_global_load_lds(
      (const __attribute__((address_space(1))) void*)g,
      (__attribute__((address_space(3))) void*)l, 16, 0, 0);
}

// ============================================================================
// Round-4 proven GEMM core: 128x128 tile, 256 threads (4 waves, 2M x 2N),
// BK=64, double-buffered LDS = 64 KiB -> 2 blocks/CU. LDS swizzle: 16B chunk
// c of row r at phys chunk c^(r&7) (2-way bank alias = free; 0 conflicts
// measured r4). Staging pre-swizzles the GLOBAL source (global_load_lds
// writes linearly). One __syncthreads per K-tile; the drain is masked by the
// co-resident block (m114 overlap).
// ============================================================================

__device__ __forceinline__ const unsigned short* sptr(
    const unsigned short* base, int row0, int t) {
  const int rr = t >> 3;
  const int ck = (t & 7) ^ (rr & 7);
  return base + (size_t)(row0 + rr) * D_MODEL + ck * 8;
}

#define STG8(KT, BUF) {                                                    \
    const unsigned short* a_ = sA + (KT) * 64;                             \
    const unsigned short* b_ = sB + (KT) * 64;                             \
    unsigned short* da_ = As + (BUF) * 8192 + t * 8;                       \
    unsigned short* db_ = Bs + (BUF) * 8192 + t * 8;                       \
    async_cp16(a_,                 da_);                                   \
    async_cp16(a_ + 32 * D_MODEL,  da_ + 2048);                            \
    async_cp16(a_ + 64 * D_MODEL,  da_ + 4096);                            \
    async_cp16(a_ + 96 * D_MODEL,  da_ + 6144);                            \
    async_cp16(b_,                 db_);                                   \
    async_cp16(b_ + 32 * D_MODEL,  db_ + 2048);                            \
    async_cp16(b_ + 64 * D_MODEL,  db_ + 4096);                            \
    async_cp16(b_ + 96 * D_MODEL,  db_ + 6144);                            \
  }

__device__ __forceinline__ void gemm128_bk64(
    const unsigned short* sA, const unsigned short* sB,
    unsigned short* As, unsigned short* Bs, int t, f32x4 acc[4][4]) {
  const int lane = t & 63, w = t >> 6;
  const int wm = w >> 1, wn = w & 1;
  const int l16 = lane & 15, quad = lane >> 4, x7 = l16 & 7;
  const int c0 = (quad ^ x7) * 8, c1 = ((4 | quad) ^ x7) * 8;

  STG8(0, 0);
  __syncthreads();

  #pragma unroll 2
  for (int kk = 0; kk < 16; ++kk) {
    const int cur = (kk & 1) * 8192;
    if (kk < 15) STG8(kk + 1, (kk & 1) ^ 1);
    bf16x8 afr[4][2], bfr[4][2];
    #pragma unroll
    for (int mt = 0; mt < 4; mt++) {
      const int base = cur + (wm * 64 + mt * 16 + l16) * 64;
      afr[mt][0] = *(const bf16x8*)(As + base + c0);
      afr[mt][1] = *(const bf16x8*)(As + base + c1);
    }
    #pragma unroll
    for (int nt = 0; nt < 4; nt++) {
      const int base = cur + (wn * 64 + nt * 16 + l16) * 64;
      bfr[nt][0] = *(const bf16x8*)(Bs + base + c0);
      bfr[nt][1] = *(const bf16x8*)(Bs + base + c1);
    }
    #pragma unroll
    for (int ks = 0; ks < 2; ks++)
      #pragma unroll
      for (int mt = 0; mt < 4; mt++)
        #pragma unroll
        for (int nt = 0; nt < 4; nt++)
          acc[mt][nt] = __builtin_amdgcn_mfma_f32_16x16x32_bf16(
              afr[mt][ks], bfr[nt][ks], acc[mt][nt], 0, 0, 0);
    __syncthreads();
  }
}

__device__ __forceinline__ void store_c_bf16(f32x4 acc[4][4],
                                             unsigned short* C, int ldc,
                                             int m0, int n0, int tid) {
  const int lane = tid & 63, w = tid >> 6;
  const int wm = w >> 1, wn = w & 1;
  const int l16 = lane & 15, quad = lane >> 4;
  #pragma unroll
  for (int mt = 0; mt < 4; mt++) {
    #pragma unroll
    for (int r = 0; r < 4; r++) {
      const int row = m0 + wm * 64 + mt * 16 + quad * 4 + r;
      unsigned short* cp = C + (size_t)row * ldc + n0 + wn * 64 + l16;
      #pragma unroll
      for (int nt = 0; nt < 4; nt++) cp[nt * 16] = f2bf(acc[mt][nt][r]);
    }
  }
}

// ---- wcvt v2: one WAVE per W row (no LDS/barrier). Grid 513 x 256. ----
// Blocks 0..511: 4 rows each (row = blk*4 + wave). Block 512 wave 0: bq.bk.
__global__ __launch_bounds__(256) void wcvt_kernel(
    const float* __restrict__ Wq, const float* __restrict__ Wk,
    const float* __restrict__ bq, const float* __restrict__ bk,
    unsigned short* __restrict__ Wqb, unsigned short* __restrict__ Wkb,
    float* __restrict__ u, float* __restrict__ v, float* __restrict__ sc) {
  const int w = threadIdx.x >> 6, l = threadIdx.x & 63;
  if (blockIdx.x < 512) {
    const int row = blockIdx.x * 4 + w;  // 0..2047
    const bool isq = row < 1024;
    const int rr = row & 1023;
    const float* W = isq ? Wq : Wk;
    const float* bias = isq ? bk : bq;
    ushort4* Wo4 = (ushort4*)((isq ? Wqb : Wkb) + (size_t)rr * D_MODEL);
    const float4* Wr4 = (const float4*)(W + (size_t)rr * D_MODEL);
    float p = 0.f;
    #pragma unroll
    for (int i = 0; i < 4; i++) {
      const int idx = i * 64 + l;
      const float4 wv = Wr4[idx];
      const float4 bv = ((const float4*)bias)[idx];
      ushort4 o;
      o.x = f2bf(wv.x); o.y = f2bf(wv.y); o.z = f2bf(wv.z); o.w = f2bf(wv.w);
      Wo4[idx] = o;
      p += wv.x * bv.x + wv.y * bv.y + wv.z * bv.z + wv.w * bv.w;
    }
    #pragma unroll
    for (int off = 32; off > 0; off >>= 1) p += __shfl_down(p, off, 64);
    if (l == 0) (isq ? u : v)[rr] = p;
  } else if (w == 0) {
    float p = 0.f;
    #pragma unroll
    for (int i = 0; i < 4; i++) {
      const int idx = i * 64 + l;
      const float4 a = ((const float4*)bq)[idx];
      const float4 b = ((const float4*)bk)[idx];
      p += a.x * b.x + a.y * b.y + a.z * b.z + a.w * b.w;
    }
    #pragma unroll
    for (int off = 32; off > 0; off >>= 1) p += __shfl_down(p, off, 64);
    if (l == 0) sc[0] = SCALE * p;
  }
}

// ---- prep_x v2: one WAVE per x row (no LDS/barrier). Grid 2048 x 256. ----
// xb=bf16(x); t=tanh(x.Wo+bo); aa=scale*(x.u)+sc; bb=scale*(x.v)
__global__ __launch_bounds__(256) void prep_x_kernel(
    const float* __restrict__ x, const float* __restrict__ Wo,
    const float* __restrict__ bo, const float* __restrict__ u,
    const float* __restrict__ v, const float* __restrict__ sc,
    unsigned short* __restrict__ xb, float* __restrict__ tb,
    float* __restrict__ aa, float* __restrict__ bb) {
  const int w = threadIdx.x >> 6, l = threadIdx.x & 63;
  const int m = blockIdx.x * 4 + w;
  const float4* xr4 = (const float4*)(x + (size_t)m * D_MODEL);
  ushort4* xo4 = (ushort4*)(xb + (size_t)m * D_MODEL);
  float p0 = 0.f, p1 = 0.f, p2 = 0.f;
  #pragma unroll
  for (int i = 0; i < 4; i++) {
    const int idx = i * 64 + l;
    const float4 xv = xr4[idx];
    const float4 wv = ((const float4*)Wo)[idx];
    const float4 uv = ((const float4*)u)[idx];
    const float4 vv = ((const float4*)v)[idx];
    ushort4 o;
    o.x = f2bf(xv.x); o.y = f2bf(xv.y); o.z = f2bf(xv.z); o.w = f2bf(xv.w);
    xo4[idx] = o;
    p0 += xv.x * wv.x + xv.y * wv.y + xv.z * wv.z + xv.w * wv.w;
    p1 += xv.x * uv.x + xv.y * uv.y + xv.z * uv.z + xv.w * uv.w;
    p2 += xv.x * vv.x + xv.y * vv.y + xv.z * vv.z + xv.w * vv.w;
  }
  #pragma unroll
  for (int off = 32; off > 0; off >>= 1) {
    p0 += __shfl_down(p0, off, 64);
    p1 += __shfl_down(p1, off, 64);
    p2 += __shfl_down(p2, off, 64);
  }
  if (l == 0) {
    tb[m] = tanhf(p0 + bo[0]);
    aa[m] = SCALE * p1 + sc[0];
    bb[m] = SCALE * p2;
  }
}

// ---- wmm: Mt[d2,d1] = sum_e Wk[d2,e]*Wq[d1,e]  (A=Wkb, B^T=Wqb) ----
__global__ __launch_bounds__(256, 2) void wmm_kernel(
    const unsigned short* __restrict__ Wkb,
    const unsigned short* __restrict__ Wqb, unsigned short* __restrict__ Mt) {
  const int m0 = blockIdx.x * 128, n0 = blockIdx.y * 128;
  __shared__ unsigned short As[2 * 8192], Bs[2 * 8192];
  const int t = threadIdx.x;
  f32x4 acc[4][4];
  #pragma unroll
  for (int i = 0; i < 4; i++)
    #pragma unroll
    for (int j = 0; j < 4; j++) acc[i][j] = f32x4{0.f, 0.f, 0.f, 0.f};
  gemm128_bk64(sptr(Wkb, m0, t), sptr(Wqb, n0, t), As, Bs, t, acc);
  store_c_bf16(acc, Mt, D_MODEL, m0, n0, t);
}

// ---- zgen: Zb = xb @ M  (B^T = Mt rows), XCD-rectangle map (r7) ----
__global__ __launch_bounds__(256, 2) void zgen_kernel(
    const unsigned short* __restrict__ xb,
    const unsigned short* __restrict__ Mt, unsigned short* __restrict__ Zb) {
  const int id = blockIdx.y * 64 + blockIdx.x;
  const int xcd = id & 7, q = id >> 3;
  const int m0 = (xcd * 8 + (q & 7)) * 128;
  const int n0 = (q >> 3) * 128;
  __shared__ unsigned short As[2 * 8192], Bs[2 * 8192];
  const int t = threadIdx.x;
  f32x4 acc[4][4];
  #pragma unroll
  for (int i = 0; i < 4; i++)
    #pragma unroll
    for (int j = 0; j < 4; j++) acc[i][j] = f32x4{0.f, 0.f, 0.f, 0.f};
  gemm128_bk64(sptr(xb, m0, t), sptr(Mt, n0, t), As, Bs, t, acc);
  store_c_bf16(acc, Zb, D_MODEL, m0, n0, t);
}

// ---- zxt: round-4-exact core + T1 XCD rectangle map ----
// out[b,i,j] = scale*(Z_i . x_j) + aa_i + bb_j + 5*tanh(s_j-s_i)
__global__ __launch_bounds__(256, 2) void zxt_kernel(
    const unsigned short* __restrict__ Zb, const unsigned short* __restrict__ xb,
    const float* __restrict__ tb, const float* __restrict__ aa,
    const float* __restrict__ bb, float* __restrict__ out) {
  __shared__ unsigned short As[2 * 8192], Bs[2 * 8192];
  __shared__ float tsi[128], tsa[128], tsj[128], tsb2[128];
  const int n = blockIdx.z * 256 + blockIdx.y * 16 + blockIdx.x;
  const int xcd = n & 7, q = n >> 3;
  const int b = q >> 5, r = q & 31;
  const int i0 = ((xcd >> 1) * 4 + (r >> 3)) * 128;
  const int j0 = ((xcd & 1) * 8 + (r & 7)) * 128;
  const int t = threadIdx.x;

  // bias vectors up front (core's __syncthreads drains cover them)
  if (t < 128) {
    tsi[t] = tb[b * SEQ + i0 + t];
    tsa[t] = aa[b * SEQ + i0 + t];
  } else {
    tsj[t - 128] = tb[b * SEQ + j0 + t - 128];
    tsb2[t - 128] = bb[b * SEQ + j0 + t - 128];
  }

  f32x4 acc[4][4];
  #pragma unroll
  for (int i = 0; i < 4; i++)
    #pragma unroll
    for (int j = 0; j < 4; j++) acc[i][j] = f32x4{0.f, 0.f, 0.f, 0.f};
  gemm128_bk64(sptr(Zb + (size_t)b * SEQ * D_MODEL, i0, t),
               sptr(xb + (size_t)b * SEQ * D_MODEL, j0, t), As, Bs, t, acc);

  const int lane = t & 63, w = t >> 6;
  const int wm = w >> 1, wn = w & 1;
  const int l16 = lane & 15, quad = lane >> 4;
  float tj[4], bj[4];
  #pragma unroll
  for (int nt = 0; nt < 4; nt++) {
    tj[nt] = tsj[wn * 64 + nt * 16 + l16];
    bj[nt] = tsb2[wn * 64 + nt * 16 + l16];
  }
  #pragma unroll
  for (int mt = 0; mt < 4; mt++) {
    #pragma unroll
    for (int rr = 0; rr < 4; rr++) {
      const int il = wm * 64 + mt * 16 + quad * 4 + rr;
      const float ti = tsi[il];
      const float ai = tsa[il];
      float* cp =
          out + ((size_t)(b * SEQ + i0 + il)) * SEQ + j0 + wn * 64 + l16;
      #pragma unroll
      for (int nt = 0; nt < 4; nt++) {
        const float num = tj[nt] - ti;
        const float den = fmaf(-tj[nt], ti, 1.0f);
        const float obias = 5.0f * num * __builtin_amdgcn_rcpf(den);
        cp[nt * 16] = SCALE * acc[mt][nt][rr] + ai + bj[nt] + obias;
      }
    }
  }
}

extern "C" void kernel_launch(void* const* d_in, const int* in_sizes, int n_in,
                              void* d_out, int out_size, void* d_ws,
                              size_t ws_size, hipStream_t stream) {
  const float* x  = (const float*)d_in[0];
  const float* Wq = (const float*)d_in[1];
  const float* bq = (const float*)d_in[2];
  const float* Wk = (const float*)d_in[3];
  const float* bk = (const float*)d_in[4];
  const float* Wo = (const float*)d_in[5];
  const float* bo = (const float*)d_in[6];
  float* out = (float*)d_out;

  char* ws = (char*)d_ws;
  unsigned short* xb  = (unsigned short*)(ws);                      // 16 MiB
  unsigned short* Zb  = (unsigned short*)(ws + (16ull << 20));      // 16 MiB
  unsigned short* Wqb = (unsigned short*)(ws + (32ull << 20));      // 2 MiB
  unsigned short* Wkb = (unsigned short*)(ws + (34ull << 20));      // 2 MiB
  unsigned short* Mt  = (unsigned short*)(ws + (36ull << 20));      // 2 MiB
  float* tb = (float*)(ws + (38ull << 20));                         // 32 KiB
  float* aa = (float*)(ws + (38ull << 20) + (32ull << 10));         // 32 KiB
  float* bb = (float*)(ws + (38ull << 20) + (64ull << 10));         // 32 KiB
  float* u  = (float*)(ws + (38ull << 20) + (96ull << 10));         // 4 KiB
  float* v  = (float*)(ws + (38ull << 20) + (100ull << 10));        // 4 KiB
  float* sc = (float*)(ws + (38ull << 20) + (104ull << 10));        // 4 B

  wcvt_kernel<<<513, 256, 0, stream>>>(Wq, Wk, bq, bk, Wqb, Wkb, u, v, sc);
  prep_x_kernel<<<2048, 256, 0, stream>>>(x, Wo, bo, u, v, sc, xb, tb, aa, bb);
  wmm_kernel<<<dim3(8, 8), 256, 0, stream>>>(Wkb, Wqb, Mt);
  zgen_kernel<<<dim3(64, 8), 256, 0, stream>>>(xb, Mt, Zb);
  zxt_kernel<<<dim3(16, 16, 4), 256, 0, stream>>>(Zb, xb, tb, aa, bb, out);
}

// Round 9
// 178.588 us; speedup vs baseline: 2.0884x; 1.0312x over previous
//
#include <hip/hip_runtime.h>
#include <math.h>

#define D_MODEL 1024
#define SEQ 2048
#define SCALE 0.03125f

using bf16x8 = __attribute__((ext_vector_type(8))) short;
using f32x4  = __attribute__((ext_vector_type(4))) float;

__device__ __forceinline__ unsigned short f2bf(float f) {
  union { float f; unsigned int u; } v; v.f = f;
  return (unsigned short)((v.u + 0x7fffu + ((v.u >> 16) & 1u)) >> 16);
}

__device__ __forceinline__ void async_cp16(const void* g, void* l) {
  __builtin_amdgcn_global_load_lds(
      (const __attribute__((address_space(1))) void*)g,
      (__attribute__((address_space(3))) void*)l, 16, 0, 0);
}

// ============================================================================
// Round-4 proven GEMM core: 128x128 tile, 256 threads (4 waves, 2M x 2N),
// BK=64, double-buffered LDS = 64 KiB -> 2 blocks/CU. LDS swizzle: 16B chunk
// c of row r at phys chunk c^(r&7) (2-way bank alias = free; 0 conflicts
// measured). Staging pre-swizzles the GLOBAL source (global_load_lds writes
// linearly). One __syncthreads per K-tile; drain masked by co-resident block.
// ============================================================================

__device__ __forceinline__ const unsigned short* sptr(
    const unsigned short* base, int row0, int t) {
  const int rr = t >> 3;
  const int ck = (t & 7) ^ (rr & 7);
  return base + (size_t)(row0 + rr) * D_MODEL + ck * 8;
}

#define STG8(KT, BUF) {                                                    \
    const unsigned short* a_ = sA + (KT) * 64;                             \
    const unsigned short* b_ = sB + (KT) * 64;                             \
    unsigned short* da_ = As + (BUF) * 8192 + t * 8;                       \
    unsigned short* db_ = Bs + (BUF) * 8192 + t * 8;                       \
    async_cp16(a_,                 da_);                                   \
    async_cp16(a_ + 32 * D_MODEL,  da_ + 2048);                            \
    async_cp16(a_ + 64 * D_MODEL,  da_ + 4096);                            \
    async_cp16(a_ + 96 * D_MODEL,  da_ + 6144);                            \
    async_cp16(b_,                 db_);                                   \
    async_cp16(b_ + 32 * D_MODEL,  db_ + 2048);                            \
    async_cp16(b_ + 64 * D_MODEL,  db_ + 4096);                            \
    async_cp16(b_ + 96 * D_MODEL,  db_ + 6144);                            \
  }

__device__ __forceinline__ void gemm128_bk64(
    const unsigned short* sA, const unsigned short* sB,
    unsigned short* As, unsigned short* Bs, int t, f32x4 acc[4][4]) {
  const int lane = t & 63, w = t >> 6;
  const int wm = w >> 1, wn = w & 1;
  const int l16 = lane & 15, quad = lane >> 4, x7 = l16 & 7;
  const int c0 = (quad ^ x7) * 8, c1 = ((4 | quad) ^ x7) * 8;

  STG8(0, 0);
  __syncthreads();

  #pragma unroll 2
  for (int kk = 0; kk < 16; ++kk) {
    const int cur = (kk & 1) * 8192;
    if (kk < 15) STG8(kk + 1, (kk & 1) ^ 1);
    bf16x8 afr[4][2], bfr[4][2];
    #pragma unroll
    for (int mt = 0; mt < 4; mt++) {
      const int base = cur + (wm * 64 + mt * 16 + l16) * 64;
      afr[mt][0] = *(const bf16x8*)(As + base + c0);
      afr[mt][1] = *(const bf16x8*)(As + base + c1);
    }
    #pragma unroll
    for (int nt = 0; nt < 4; nt++) {
      const int base = cur + (wn * 64 + nt * 16 + l16) * 64;
      bfr[nt][0] = *(const bf16x8*)(Bs + base + c0);
      bfr[nt][1] = *(const bf16x8*)(Bs + base + c1);
    }
    #pragma unroll
    for (int ks = 0; ks < 2; ks++)
      #pragma unroll
      for (int mt = 0; mt < 4; mt++)
        #pragma unroll
        for (int nt = 0; nt < 4; nt++)
          acc[mt][nt] = __builtin_amdgcn_mfma_f32_16x16x32_bf16(
              afr[mt][ks], bfr[nt][ks], acc[mt][nt], 0, 0, 0);
    __syncthreads();
  }
}

__device__ __forceinline__ void store_c_bf16(f32x4 acc[4][4],
                                             unsigned short* C, int ldc,
                                             int m0, int n0, int tid) {
  const int lane = tid & 63, w = tid >> 6;
  const int wm = w >> 1, wn = w & 1;
  const int l16 = lane & 15, quad = lane >> 4;
  #pragma unroll
  for (int mt = 0; mt < 4; mt++) {
    #pragma unroll
    for (int r = 0; r < 4; r++) {
      const int row = m0 + wm * 64 + mt * 16 + quad * 4 + r;
      unsigned short* cp = C + (size_t)row * ldc + n0 + wn * 64 + l16;
      #pragma unroll
      for (int nt = 0; nt < 4; nt++) cp[nt * 16] = f2bf(acc[mt][nt][r]);
    }
  }
}

// ---- wcvt v2 (r8 proven): one WAVE per W row. Grid 513 x 256. ----
__global__ __launch_bounds__(256) void wcvt_kernel(
    const float* __restrict__ Wq, const float* __restrict__ Wk,
    const float* __restrict__ bq, const float* __restrict__ bk,
    unsigned short* __restrict__ Wqb, unsigned short* __restrict__ Wkb,
    float* __restrict__ u, float* __restrict__ v, float* __restrict__ sc) {
  const int w = threadIdx.x >> 6, l = threadIdx.x & 63;
  if (blockIdx.x < 512) {
    const int row = blockIdx.x * 4 + w;  // 0..2047
    const bool isq = row < 1024;
    const int rr = row & 1023;
    const float* W = isq ? Wq : Wk;
    const float* bias = isq ? bk : bq;
    ushort4* Wo4 = (ushort4*)((isq ? Wqb : Wkb) + (size_t)rr * D_MODEL);
    const float4* Wr4 = (const float4*)(W + (size_t)rr * D_MODEL);
    float p = 0.f;
    #pragma unroll
    for (int i = 0; i < 4; i++) {
      const int idx = i * 64 + l;
      const float4 wv = Wr4[idx];
      const float4 bv = ((const float4*)bias)[idx];
      ushort4 o;
      o.x = f2bf(wv.x); o.y = f2bf(wv.y); o.z = f2bf(wv.z); o.w = f2bf(wv.w);
      Wo4[idx] = o;
      p += wv.x * bv.x + wv.y * bv.y + wv.z * bv.z + wv.w * bv.w;
    }
    #pragma unroll
    for (int off = 32; off > 0; off >>= 1) p += __shfl_down(p, off, 64);
    if (l == 0) (isq ? u : v)[rr] = p;
  } else if (w == 0) {
    float p = 0.f;
    #pragma unroll
    for (int i = 0; i < 4; i++) {
      const int idx = i * 64 + l;
      const float4 a = ((const float4*)bq)[idx];
      const float4 b = ((const float4*)bk)[idx];
      p += a.x * b.x + a.y * b.y + a.z * b.z + a.w * b.w;
    }
    #pragma unroll
    for (int off = 32; off > 0; off >>= 1) p += __shfl_down(p, off, 64);
    if (l == 0) sc[0] = SCALE * p;
  }
}

// ---- prep_x v2 (r8 proven): one WAVE per x row. Grid 2048 x 256. ----
__global__ __launch_bounds__(256) void prep_x_kernel(
    const float* __restrict__ x, const float* __restrict__ Wo,
    const float* __restrict__ bo, const float* __restrict__ u,
    const float* __restrict__ v, const float* __restrict__ sc,
    unsigned short* __restrict__ xb, float* __restrict__ tb,
    float* __restrict__ aa, float* __restrict__ bb) {
  const int w = threadIdx.x >> 6, l = threadIdx.x & 63;
  const int m = blockIdx.x * 4 + w;
  const float4* xr4 = (const float4*)(x + (size_t)m * D_MODEL);
  ushort4* xo4 = (ushort4*)(xb + (size_t)m * D_MODEL);
  float p0 = 0.f, p1 = 0.f, p2 = 0.f;
  #pragma unroll
  for (int i = 0; i < 4; i++) {
    const int idx = i * 64 + l;
    const float4 xv = xr4[idx];
    const float4 wv = ((const float4*)Wo)[idx];
    const float4 uv = ((const float4*)u)[idx];
    const float4 vv = ((const float4*)v)[idx];
    ushort4 o;
    o.x = f2bf(xv.x); o.y = f2bf(xv.y); o.z = f2bf(xv.z); o.w = f2bf(xv.w);
    xo4[idx] = o;
    p0 += xv.x * wv.x + xv.y * wv.y + xv.z * wv.z + xv.w * wv.w;
    p1 += xv.x * uv.x + xv.y * uv.y + xv.z * uv.z + xv.w * uv.w;
    p2 += xv.x * vv.x + xv.y * vv.y + xv.z * vv.z + xv.w * vv.w;
  }
  #pragma unroll
  for (int off = 32; off > 0; off >>= 1) {
    p0 += __shfl_down(p0, off, 64);
    p1 += __shfl_down(p1, off, 64);
    p2 += __shfl_down(p2, off, 64);
  }
  if (l == 0) {
    tb[m] = tanhf(p0 + bo[0]);
    aa[m] = SCALE * p1 + sc[0];
    bb[m] = SCALE * p2;
  }
}

// ---- wmm v2: 64x64 tiles -> 256 blocks (latency-bound fix). ----
// Same BK=64, same chunk-XOR swizzle family (8 x 16B chunks per row, phys
// chunk = c^(r&7)); per wave 32x32 out (acc[2][2]); LDS 32 KiB dbuf.
// Mt[d2,d1] = sum_e Wkb[d2,e] * Wqb[d1,e].
__global__ __launch_bounds__(256, 2) void wmm_kernel(
    const unsigned short* __restrict__ Wkb,
    const unsigned short* __restrict__ Wqb, unsigned short* __restrict__ Mt) {
  const int m0 = blockIdx.x * 64, n0 = blockIdx.y * 64;
  __shared__ unsigned short As[2 * 4096], Bs[2 * 4096];
  const int t = threadIdx.x;
  const int lane = t & 63, w = t >> 6;
  const int wm = w >> 1, wn = w & 1;
  const int l16 = lane & 15, quad = lane >> 4, x7 = l16 & 7;
  const int c0 = (quad ^ x7) * 8, c1 = ((4 | quad) ^ x7) * 8;
  const unsigned short* sA = sptr(Wkb, m0, t);
  const unsigned short* sB = sptr(Wqb, n0, t);

  #define STG4W(KT, BUF) {                                                 \
      const unsigned short* a_ = sA + (KT) * 64;                           \
      const unsigned short* b_ = sB + (KT) * 64;                           \
      unsigned short* da_ = As + (BUF) * 4096 + t * 8;                     \
      unsigned short* db_ = Bs + (BUF) * 4096 + t * 8;                     \
      async_cp16(a_,                da_);                                  \
      async_cp16(a_ + 32 * D_MODEL, da_ + 2048);                           \
      async_cp16(b_,                db_);                                  \
      async_cp16(b_ + 32 * D_MODEL, db_ + 2048);                           \
    }

  f32x4 acc[2][2];
  #pragma unroll
  for (int i = 0; i < 2; i++)
    #pragma unroll
    for (int j = 0; j < 2; j++) acc[i][j] = f32x4{0.f, 0.f, 0.f, 0.f};

  STG4W(0, 0);
  __syncthreads();
  #pragma unroll 2
  for (int kk = 0; kk < 16; ++kk) {
    const int cur = (kk & 1) * 4096;
    if (kk < 15) STG4W(kk + 1, (kk & 1) ^ 1);
    bf16x8 afr[2][2], bfr[2][2];
    #pragma unroll
    for (int mt = 0; mt < 2; mt++) {
      const int base = cur + (wm * 32 + mt * 16 + l16) * 64;
      afr[mt][0] = *(const bf16x8*)(As + base + c0);
      afr[mt][1] = *(const bf16x8*)(As + base + c1);
    }
    #pragma unroll
    for (int nt = 0; nt < 2; nt++) {
      const int base = cur + (wn * 32 + nt * 16 + l16) * 64;
      bfr[nt][0] = *(const bf16x8*)(Bs + base + c0);
      bfr[nt][1] = *(const bf16x8*)(Bs + base + c1);
    }
    #pragma unroll
    for (int ks = 0; ks < 2; ks++)
      #pragma unroll
      for (int mt = 0; mt < 2; mt++)
        #pragma unroll
        for (int nt = 0; nt < 2; nt++)
          acc[mt][nt] = __builtin_amdgcn_mfma_f32_16x16x32_bf16(
              afr[mt][ks], bfr[nt][ks], acc[mt][nt], 0, 0, 0);
    __syncthreads();
  }

  #pragma unroll
  for (int mt = 0; mt < 2; mt++) {
    #pragma unroll
    for (int r = 0; r < 4; r++) {
      const int row = m0 + wm * 32 + mt * 16 + quad * 4 + r;
      unsigned short* cp = Mt + (size_t)row * D_MODEL + n0 + wn * 32 + l16;
      #pragma unroll
      for (int nt = 0; nt < 2; nt++) cp[nt * 16] = f2bf(acc[mt][nt][r]);
    }
  }
}

// ---- zgen: Zb = xb @ M  (B^T = Mt rows), XCD-rectangle map (r7/r8) ----
__global__ __launch_bounds__(256, 2) void zgen_kernel(
    const unsigned short* __restrict__ xb,
    const unsigned short* __restrict__ Mt, unsigned short* __restrict__ Zb) {
  const int id = blockIdx.y * 64 + blockIdx.x;
  const int xcd = id & 7, q = id >> 3;
  const int m0 = (xcd * 8 + (q & 7)) * 128;
  const int n0 = (q >> 3) * 128;
  __shared__ unsigned short As[2 * 8192], Bs[2 * 8192];
  const int t = threadIdx.x;
  f32x4 acc[4][4];
  #pragma unroll
  for (int i = 0; i < 4; i++)
    #pragma unroll
    for (int j = 0; j < 4; j++) acc[i][j] = f32x4{0.f, 0.f, 0.f, 0.f};
  gemm128_bk64(sptr(xb, m0, t), sptr(Mt, n0, t), As, Bs, t, acc);
  store_c_bf16(acc, Zb, D_MODEL, m0, n0, t);
}

// ---- zxt: round-4-exact core + T1 XCD rectangle map ----
__global__ __launch_bounds__(256, 2) void zxt_kernel(
    const unsigned short* __restrict__ Zb, const unsigned short* __restrict__ xb,
    const float* __restrict__ tb, const float* __restrict__ aa,
    const float* __restrict__ bb, float* __restrict__ out) {
  __shared__ unsigned short As[2 * 8192], Bs[2 * 8192];
  __shared__ float tsi[128], tsa[128], tsj[128], tsb2[128];
  const int n = blockIdx.z * 256 + blockIdx.y * 16 + blockIdx.x;
  const int xcd = n & 7, q = n >> 3;
  const int b = q >> 5, r = q & 31;
  const int i0 = ((xcd >> 1) * 4 + (r >> 3)) * 128;
  const int j0 = ((xcd & 1) * 8 + (r & 7)) * 128;
  const int t = threadIdx.x;

  if (t < 128) {
    tsi[t] = tb[b * SEQ + i0 + t];
    tsa[t] = aa[b * SEQ + i0 + t];
  } else {
    tsj[t - 128] = tb[b * SEQ + j0 + t - 128];
    tsb2[t - 128] = bb[b * SEQ + j0 + t - 128];
  }

  f32x4 acc[4][4];
  #pragma unroll
  for (int i = 0; i < 4; i++)
    #pragma unroll
    for (int j = 0; j < 4; j++) acc[i][j] = f32x4{0.f, 0.f, 0.f, 0.f};
  gemm128_bk64(sptr(Zb + (size_t)b * SEQ * D_MODEL, i0, t),
               sptr(xb + (size_t)b * SEQ * D_MODEL, j0, t), As, Bs, t, acc);

  const int lane = t & 63, w = t >> 6;
  const int wm = w >> 1, wn = w & 1;
  const int l16 = lane & 15, quad = lane >> 4;
  float tj[4], bj[4];
  #pragma unroll
  for (int nt = 0; nt < 4; nt++) {
    tj[nt] = tsj[wn * 64 + nt * 16 + l16];
    bj[nt] = tsb2[wn * 64 + nt * 16 + l16];
  }
  #pragma unroll
  for (int mt = 0; mt < 4; mt++) {
    #pragma unroll
    for (int rr = 0; rr < 4; rr++) {
      const int il = wm * 64 + mt * 16 + quad * 4 + rr;
      const float ti = tsi[il];
      const float ai = tsa[il];
      float* cp =
          out + ((size_t)(b * SEQ + i0 + il)) * SEQ + j0 + wn * 64 + l16;
      #pragma unroll
      for (int nt = 0; nt < 4; nt++) {
        const float num = tj[nt] - ti;
        const float den = fmaf(-tj[nt], ti, 1.0f);
        const float obias = 5.0f * num * __builtin_amdgcn_rcpf(den);
        cp[nt * 16] = SCALE * acc[mt][nt][rr] + ai + bj[nt] + obias;
      }
    }
  }
}

extern "C" void kernel_launch(void* const* d_in, const int* in_sizes, int n_in,
                              void* d_out, int out_size, void* d_ws,
                              size_t ws_size, hipStream_t stream) {
  const float* x  = (const float*)d_in[0];
  const float* Wq = (const float*)d_in[1];
  const float* bq = (const float*)d_in[2];
  const float* Wk = (const float*)d_in[3];
  const float* bk = (const float*)d_in[4];
  const float* Wo = (const float*)d_in[5];
  const float* bo = (const float*)d_in[6];
  float* out = (float*)d_out;

  char* ws = (char*)d_ws;
  unsigned short* xb  = (unsigned short*)(ws);                      // 16 MiB
  unsigned short* Zb  = (unsigned short*)(ws + (16ull << 20));      // 16 MiB
  unsigned short* Wqb = (unsigned short*)(ws + (32ull << 20));      // 2 MiB
  unsigned short* Wkb = (unsigned short*)(ws + (34ull << 20));      // 2 MiB
  unsigned short* Mt  = (unsigned short*)(ws + (36ull << 20));      // 2 MiB
  float* tb = (float*)(ws + (38ull << 20));                         // 32 KiB
  float* aa = (float*)(ws + (38ull << 20) + (32ull << 10));         // 32 KiB
  float* bb = (float*)(ws + (38ull << 20) + (64ull << 10));         // 32 KiB
  float* u  = (float*)(ws + (38ull << 20) + (96ull << 10));         // 4 KiB
  float* v  = (float*)(ws + (38ull << 20) + (100ull << 10));        // 4 KiB
  float* sc = (float*)(ws + (38ull << 20) + (104ull << 10));        // 4 B

  wcvt_kernel<<<513, 256, 0, stream>>>(Wq, Wk, bq, bk, Wqb, Wkb, u, v, sc);
  prep_x_kernel<<<2048, 256, 0, stream>>>(x, Wo, bo, u, v, sc, xb, tb, aa, bb);
  wmm_kernel<<<dim3(16, 16), 256, 0, stream>>>(Wkb, Wqb, Mt);
  zgen_kernel<<<dim3(64, 8), 256, 0, stream>>>(xb, Mt, Zb);
  zxt_kernel<<<dim3(16, 16, 4), 256, 0, stream>>>(Zb, xb, tb, aa, bb, out);
}